// Round 1
// baseline (741.030 us; speedup 1.0000x reference)
//
#include <hip/hip_runtime.h>
#include <hip/hip_bf16.h>
#include <stdint.h>

// Mahalanobis loss via Gram reformulation:
//   mean_n (f_n-mu)^T C (f_n-mu)
//     = (1/N)[ <C, G> - sum_{d,e} C_de (coef_d mu_e + mu_d coef_e) ],
//   G = Fb^T Fb (bf16 inputs, fp32 accum), s = sum_n fb_n, coef = s - (N/2) mu.
// R4 (this round): kernel was latency-bound (all pipes ~10%, occupancy 18.6%
// capped at 25% by LDS with 256-thread blocks). Same 74.5KB LDS now hosts
// 512-thread blocks -> 16 waves/CU resident (2 blocks). 8 waves = 2x2 spatial
// grid x 2-way K-split (K-partials contract with C into the same scalar, so
// no cross-wave combine needed); per-block DS-read traffic unchanged
// (64 b128/iter). Staging remapped to 256 thr/matrix, bank rotations
// re-derived (16-lane groups of each b64 write hit 16 distinct bank-pairs,
// enumerated). Diagonal tiles stage As only (Bs identical) -> -20% LDS
// writes, -10% global loads. __launch_bounds__(512,4): 4 waves/EU -> VGPR
// cap 128, k = 4*4/(512/64) = 2 blocks/CU.

typedef __attribute__((ext_vector_type(8))) short short8;
typedef __attribute__((ext_vector_type(4))) short short4v;
typedef __attribute__((ext_vector_type(4))) float floatx4;

static constexpr int NROWS = 131072;
static constexpr int DDIM  = 512;
static constexpr int AST   = 72;          // LDS row stride in shorts (64 n + 8 pad)
static constexpr int SLOT  = 128 * AST;   // shorts per double-buffer slot

__device__ __forceinline__ short f2bf(float f) {
  __bf16 b = (__bf16)f;                   // RNE f32->bf16
  return __builtin_bit_cast(short, b);
}
__device__ __forceinline__ float bf2f(short s) {
  __bf16 b = __builtin_bit_cast(__bf16, s);
  return (float)b;
}

// ---- zero-init: s[512] and out (both poisoned 0xAA before every launch) ----
__global__ __launch_bounds__(512) void maha_zero(float* __restrict__ s_ws,
                                                 float* __restrict__ out) {
  s_ws[threadIdx.x] = 0.0f;
  if (threadIdx.x == 0) out[0] = 0.0f;
}

// ---- main: symmetric Gram tiles, fused <C,G> epilogue + s accumulation ----
__global__ __launch_bounds__(512, 4) void maha_gram(const float* __restrict__ F,
                                                    const float* __restrict__ C,
                                                    float* __restrict__ s_ws,
                                                    float* __restrict__ out) {
  // As = ABs[0..2*SLOT) : F columns [128*ti,+128), [d][n] bf16, double-buffered
  // Bs = ABs[2*SLOT..)  : F columns [128*tj,+128)  (unused when diag)
  __shared__ short ABs[4 * SLOT];
  __shared__ float sred[1024];
  __shared__ float red[8];

  static const int TI[10] = {0,0,0,0,1,1,1,2,2,3};
  static const int TJ[10] = {0,1,2,3,1,2,3,2,3,3};

  // swizzle: groups of 80 = 8 slabs x 10 tiles; co-slab blocks share bid%8
  // (same XCD) and sit within one 80-bid window (temporal locality in L2).
  const int bid  = blockIdx.x;
  const int gg   = bid / 80;
  const int rr   = bid % 80;
  const int slab = gg * 8 + (rr & 7);     // 0..127, 1024 rows each
  const int tile = rr >> 3;               // 0..9
  const int ti = TI[tile], tj = TJ[tile];
  const bool diag = (ti == tj);

  const int th = threadIdx.x;
  // ---- staging mapping: 256 threads per matrix (As / Bs) ----
  const int half = th >> 8;               // 0 -> As, 1 -> Bs
  const int t2   = th & 255;
  const int tp   = t2 & 31;               // d-quad owner (d = 4*tp + dd)
  const int tn   = t2 >> 5;               // 0..7
  const int colbase = 128 * (half ? tj : ti);
  short* mybuf = ABs + (half ? 2 * SLOT : 0);
  const bool skipstage = diag && (half == 1);  // diag: Bs slab == As slab

  // rotations for conflict-free b64 LDS writes (16 distinct bank-pairs per
  // 16-lane group; enumerated for tn=0..3 x kq=0/1):
  const int tphi = (tp >> 4) & 1;         // k rotation (bit 4 of tp)
  const int noff = (tn + (tp >> 2)) & 7;  // n-sub rotation (bits 2-4 of tp)
  const int gsw  = 8 * (tp & 7);          // XOR address swizzle = 8*((d>>2)&7)

  const float* gbase = F + (size_t)slab * 1024 * DDIM + colbase + 4 * tp;

  floatx4 v[2][4];                        // single fp32 prefetch stage (32 VGPR)

  auto loadG = [&](int c) {
    if (skipstage) return;
#pragma unroll
    for (int k = 0; k < 2; k++) {
      const int kq = k ^ tphi;
      const int nb = 8 * kq + noff;       // n-block 0..15 within the 64-row chunk
      const float* p = gbase + (size_t)(c * 64 + 4 * nb) * DDIM;
#pragma unroll
      for (int nn = 0; nn < 4; nn++)
        v[k][nn] = *(const floatx4*)(p + nn * DDIM);
    }
  };

  float s_part[4] = {0.f, 0.f, 0.f, 0.f};
  const bool sacc = diag && (half == 0);  // diag blocks accumulate s once per col

  auto cvtwrite = [&](int slot) {
    if (skipstage) return;
#pragma unroll
    for (int k = 0; k < 2; k++) {
      const int kq = k ^ tphi;
      const int nb = 8 * kq + noff;
      const int naddr = (4 * nb) ^ gsw;   // XOR bits>=3 only: 4-runs move as units
#pragma unroll
      for (int dd = 0; dd < 4; dd++) {
        short4v pk;                        // register 4x4 transpose: column dd
        pk[0] = f2bf(v[k][0][dd]); pk[1] = f2bf(v[k][1][dd]);
        pk[2] = f2bf(v[k][2][dd]); pk[3] = f2bf(v[k][3][dd]);
        *(short4v*)&mybuf[slot * SLOT + (4 * tp + dd) * AST + naddr] = pk;
        if (sacc)
          s_part[dd] += bf2f(pk[0]) + bf2f(pk[1]) + bf2f(pk[2]) + bf2f(pk[3]);
      }
    }
  };

  // ---- MFMA mapping: 2x2 spatial wave grid x 2-way K-split over 128x128 ----
  const int wave = th >> 6, lane = th & 63;
  const int wk = wave & 1;                // k-half of the 64-row chunk
  const int wm = (wave >> 1) & 1;
  const int wn = (wave >> 2) & 1;
  const int l15 = lane & 15, quad = lane >> 4;
  const int kcol = wk * 32 + quad * 8;    // bf16 column offset of the K=32 slice

  const short* Ard = ABs;
  const short* Brd = ABs + (diag ? 0 : 2 * SLOT);

  int aoff[4], swA[4], boff[4], swB[4];
#pragma unroll
  for (int mi = 0; mi < 4; mi++) {
    const int d = wm * 64 + mi * 16 + l15;
    aoff[mi] = d * AST;  swA[mi] = 8 * ((d >> 2) & 7);
    const int e = wn * 64 + mi * 16 + l15;
    boff[mi] = e * AST;  swB[mi] = 8 * ((e >> 2) & 7);
  }

  floatx4 acc[4][4];
#pragma unroll
  for (int i = 0; i < 4; i++)
#pragma unroll
    for (int j = 0; j < 4; j++) acc[i][j] = floatx4{0.f, 0.f, 0.f, 0.f};

  loadG(0);
  cvtwrite(0);
  loadG(1);

#pragma unroll 2
  for (int c = 0; c < 16; ++c) {
    const int slot = c & 1;
    __syncthreads();                      // slot ready; other slot free
    short8 af[4], bfr[4];
#pragma unroll
    for (int mi = 0; mi < 4; mi++)
      af[mi] = *(const short8*)&Ard[slot * SLOT + aoff[mi] + (kcol ^ swA[mi])];
#pragma unroll
    for (int fj = 0; fj < 4; fj++)
      bfr[fj] = *(const short8*)&Brd[slot * SLOT + boff[fj] + (kcol ^ swB[fj])];
    if (c < 15) cvtwrite(slot ^ 1);       // chunk c+1 (regs loaded at iter c-1)
    if (c < 14) loadG(c + 2);             // issued BEFORE MFMA: ~1 iter of flight
#pragma unroll
    for (int mi = 0; mi < 4; mi++)
#pragma unroll
      for (int fj = 0; fj < 4; fj++)
        acc[mi][fj] = __builtin_amdgcn_mfma_f32_16x16x32_bf16(
            af[mi], bfr[fj], acc[mi][fj], 0, 0, 0);
  }

  // ---- epilogue: psum = sum W_de * G_de, W = C_ij (+ C_ji^T if offdiag) ----
  // K-split partners (wk=0/1) hold partial G for the same (d,e) region; both
  // contract with the same C weights -> psum adds correctly across waves.
  const int d0 = ti * 128, e0 = tj * 128;
  float psum = 0.f;
#pragma unroll
  for (int mi = 0; mi < 4; mi++) {
#pragma unroll
    for (int fj = 0; fj < 4; fj++) {
      const int dg = d0 + wm * 64 + mi * 16 + quad * 4;
      const int eg = e0 + wn * 64 + fj * 16 + l15;
#pragma unroll
      for (int r2 = 0; r2 < 4; r2++) {
        float wgt = C[(size_t)(dg + r2) * DDIM + eg];
        if (!diag) wgt += C[(size_t)eg * DDIM + dg + r2];
        psum += wgt * acc[mi][fj][r2];
      }
    }
  }

#pragma unroll
  for (int off = 32; off > 0; off >>= 1) psum += __shfl_down(psum, off);
  if (lane == 0) red[wave] = psum;
  if (sacc) {                             // park s partials (th < 256 only)
#pragma unroll
    for (int dd = 0; dd < 4; dd++) sred[(4 * tp + dd) * 8 + tn] = s_part[dd];
  }
  __syncthreads();
  if (th == 0) {
    const float tot = red[0] + red[1] + red[2] + red[3] +
                      red[4] + red[5] + red[6] + red[7];
    atomicAdd(out, tot * (1.0f / (float)NROWS));
  }
  if (diag && th < 128) {
    float sd = 0.f;
#pragma unroll
    for (int j = 0; j < 8; j++) sd += sred[th * 8 + j];
    atomicAdd(&s_ws[ti * 128 + th], sd);
  }
}

// ---- correction: out += -(1/N) sum_{d,e} C_de (coef_d mu_e + mu_d coef_e) ----
__global__ __launch_bounds__(256) void maha_corr(const float* __restrict__ C,
                                                 const float* __restrict__ mu,
                                                 const float* __restrict__ s_ws,
                                                 float* __restrict__ out) {
  __shared__ float red[4];
  const int b = blockIdx.x;               // 128 blocks x 4 d-rows
  const int th = threadIdx.x;
  float cd[4], md[4];
#pragma unroll
  for (int dd = 0; dd < 4; dd++) {
    const int d = b * 4 + dd;
    md[dd] = mu[d];
    cd[dd] = s_ws[d] - 0.5f * (float)NROWS * md[dd];
  }
  float p = 0.f;
#pragma unroll
  for (int rep = 0; rep < 2; rep++) {
    const int e = th + rep * 256;
    const float me = mu[e];
    const float ce = s_ws[e] - 0.5f * (float)NROWS * me;
#pragma unroll
    for (int dd = 0; dd < 4; dd++)
      p += C[(size_t)(b * 4 + dd) * DDIM + e] * (cd[dd] * me + md[dd] * ce);
  }
  const int lane = th & 63, wave = th >> 6;
#pragma unroll
  for (int off = 32; off > 0; off >>= 1) p += __shfl_down(p, off);
  if (lane == 0) red[wave] = p;
  __syncthreads();
  if (th == 0)
    atomicAdd(out, -(red[0] + red[1] + red[2] + red[3]) * (1.0f / (float)NROWS));
}

extern "C" void kernel_launch(void* const* d_in, const int* in_sizes, int n_in,
                              void* d_out, int out_size, void* d_ws, size_t ws_size,
                              hipStream_t stream) {
  const float* feature = (const float*)d_in[0];   // [131072, 512] fp32
  const float* mean    = (const float*)d_in[1];   // [512] fp32
  const float* invcov  = (const float*)d_in[2];   // [512, 512] fp32
  float* out = (float*)d_out;                     // scalar fp32
  float* s_ws = (float*)d_ws;                     // s[512] fp32 (2 KB)

  maha_zero<<<1, 512, 0, stream>>>(s_ws, out);
  maha_gram<<<1280, 512, 0, stream>>>(feature, invcov, s_ws, out);
  maha_corr<<<128, 256, 0, stream>>>(invcov, mean, s_ws, out);
}

// Round 2
// 412.597 us; speedup vs baseline: 1.7960x; 1.7960x over previous
//
#include <hip/hip_runtime.h>
#include <hip/hip_bf16.h>
#include <stdint.h>

// Mahalanobis loss via Gram reformulation:
//   mean_n (f_n-mu)^T C (f_n-mu)
//     = (1/N)[ <C, G> - sum_{d,e} C_de (coef_d mu_e + mu_d coef_e) ],
//   G = Fb^T Fb (bf16 inputs, fp32 accum), s = sum_n fb_n, coef = s - (N/2) mu.
// R5: R4's 512-thread/2-blocks-per-CU structure was right (occupancy 18.6->39.7)
// but __launch_bounds__(512,4) = min 4 BLOCKS -> 64-VGPR cap -> 446 MB of spill
// writes (WRITE_SIZE counter) fully explained the 487us regression. This round:
// (512,2) -> 128-reg cap, and register demand cut to fit: 2x4 spatial wave grid
// (acc[4][2] = 32 AGPR, no K-split) + per-k-slice fragment reads (24 live frag
// regs). Peak live state ~108 regs -> no spills. Diag tiles still stage As only.

typedef __attribute__((ext_vector_type(8))) short short8;
typedef __attribute__((ext_vector_type(4))) short short4v;
typedef __attribute__((ext_vector_type(4))) float floatx4;

static constexpr int NROWS = 131072;
static constexpr int DDIM  = 512;
static constexpr int AST   = 72;          // LDS row stride in shorts (64 n + 8 pad)
static constexpr int SLOT  = 128 * AST;   // shorts per double-buffer slot

__device__ __forceinline__ short f2bf(float f) {
  __bf16 b = (__bf16)f;                   // RNE f32->bf16
  return __builtin_bit_cast(short, b);
}
__device__ __forceinline__ float bf2f(short s) {
  __bf16 b = __builtin_bit_cast(__bf16, s);
  return (float)b;
}

// ---- zero-init: s[512] and out (both poisoned 0xAA before every launch) ----
__global__ __launch_bounds__(512) void maha_zero(float* __restrict__ s_ws,
                                                 float* __restrict__ out) {
  s_ws[threadIdx.x] = 0.0f;
  if (threadIdx.x == 0) out[0] = 0.0f;
}

// ---- main: symmetric Gram tiles, fused <C,G> epilogue + s accumulation ----
__global__ __launch_bounds__(512, 2) void maha_gram(const float* __restrict__ F,
                                                    const float* __restrict__ C,
                                                    float* __restrict__ s_ws,
                                                    float* __restrict__ out) {
  // As = ABs[0..2*SLOT) : F columns [128*ti,+128), [d][n] bf16, double-buffered
  // Bs = ABs[2*SLOT..)  : F columns [128*tj,+128)  (unused when diag)
  __shared__ short ABs[4 * SLOT];
  __shared__ float sred[1024];
  __shared__ float red[8];

  static const int TI[10] = {0,0,0,0,1,1,1,2,2,3};
  static const int TJ[10] = {0,1,2,3,1,2,3,2,3,3};

  // swizzle: groups of 80 = 8 slabs x 10 tiles; co-slab blocks share bid%8
  // (same XCD) and sit within one 80-bid window (temporal locality in L2).
  const int bid  = blockIdx.x;
  const int gg   = bid / 80;
  const int rr   = bid % 80;
  const int slab = gg * 8 + (rr & 7);     // 0..127, 1024 rows each
  const int tile = rr >> 3;               // 0..9
  const int ti = TI[tile], tj = TJ[tile];
  const bool diag = (ti == tj);

  const int th = threadIdx.x;
  // ---- staging mapping: 256 threads per matrix (As / Bs) ----
  const int half = th >> 8;               // 0 -> As, 1 -> Bs
  const int t2   = th & 255;
  const int tp   = t2 & 31;               // d-quad owner (d = 4*tp + dd)
  const int tn   = t2 >> 5;               // 0..7
  const int colbase = 128 * (half ? tj : ti);
  short* mybuf = ABs + (half ? 2 * SLOT : 0);
  const bool skipstage = diag && (half == 1);  // diag: Bs slab == As slab

  // rotations for conflict-free b64 LDS writes:
  const int tphi = (tp >> 4) & 1;         // k rotation (bit 4 of tp)
  const int noff = (tn + (tp >> 2)) & 7;  // n-sub rotation (bits 2-4 of tp)
  const int gsw  = 8 * (tp & 7);          // XOR address swizzle = 8*((d>>2)&7)

  const float* gbase = F + (size_t)slab * 1024 * DDIM + colbase + 4 * tp;

  floatx4 v[2][4];                        // single fp32 prefetch stage (32 VGPR)

  auto loadG = [&](int c) {
    if (skipstage) return;
#pragma unroll
    for (int k = 0; k < 2; k++) {
      const int kq = k ^ tphi;
      const int nb = 8 * kq + noff;       // n-block 0..15 within the 64-row chunk
      const float* p = gbase + (size_t)(c * 64 + 4 * nb) * DDIM;
#pragma unroll
      for (int nn = 0; nn < 4; nn++)
        v[k][nn] = *(const floatx4*)(p + nn * DDIM);
    }
  };

  float s_part[4] = {0.f, 0.f, 0.f, 0.f};
  const bool sacc = diag && (half == 0);  // diag blocks accumulate s once per col

  auto cvtwrite = [&](int slot) {
    if (skipstage) return;
#pragma unroll
    for (int k = 0; k < 2; k++) {
      const int kq = k ^ tphi;
      const int nb = 8 * kq + noff;
      const int naddr = (4 * nb) ^ gsw;   // XOR bits>=3 only: 4-runs move as units
#pragma unroll
      for (int dd = 0; dd < 4; dd++) {
        short4v pk;                        // register 4x4 transpose: column dd
        pk[0] = f2bf(v[k][0][dd]); pk[1] = f2bf(v[k][1][dd]);
        pk[2] = f2bf(v[k][2][dd]); pk[3] = f2bf(v[k][3][dd]);
        *(short4v*)&mybuf[slot * SLOT + (4 * tp + dd) * AST + naddr] = pk;
        if (sacc)
          s_part[dd] += bf2f(pk[0]) + bf2f(pk[1]) + bf2f(pk[2]) + bf2f(pk[3]);
      }
    }
  };

  // ---- MFMA mapping: 2x4 spatial wave grid over the 128x128 G-tile ----
  const int wave = th >> 6, lane = th & 63;
  const int wm = wave >> 2;               // 0..1 -> 64 d-rows
  const int wn = wave & 3;                // 0..3 -> 32 e-cols
  const int l15 = lane & 15, quad = lane >> 4;

  const short* Ard = ABs;
  const short* Brd = ABs + (diag ? 0 : 2 * SLOT);

  int aoff[4], swA[4], boff[2], swB[2];
#pragma unroll
  for (int mi = 0; mi < 4; mi++) {
    const int d = wm * 64 + mi * 16 + l15;
    aoff[mi] = d * AST;  swA[mi] = 8 * ((d >> 2) & 7);
  }
#pragma unroll
  for (int fj = 0; fj < 2; fj++) {
    const int e = wn * 32 + fj * 16 + l15;
    boff[fj] = e * AST;  swB[fj] = 8 * ((e >> 2) & 7);
  }

  floatx4 acc[4][2];
#pragma unroll
  for (int i = 0; i < 4; i++)
#pragma unroll
    for (int j = 0; j < 2; j++) acc[i][j] = floatx4{0.f, 0.f, 0.f, 0.f};

  loadG(0);
  cvtwrite(0);
  loadG(1);

#pragma unroll 2
  for (int c = 0; c < 16; ++c) {
    const int slot = c & 1;
    __syncthreads();                      // slot ready; other slot free
    // ---- k-slice 0 fragments (24 live regs) ----
    short8 af0[4], bf0[2];
#pragma unroll
    for (int mi = 0; mi < 4; mi++)
      af0[mi] = *(const short8*)&Ard[slot * SLOT + aoff[mi] + ((quad * 8) ^ swA[mi])];
#pragma unroll
    for (int fj = 0; fj < 2; fj++)
      bf0[fj] = *(const short8*)&Brd[slot * SLOT + boff[fj] + ((quad * 8) ^ swB[fj])];
    if (c < 15) cvtwrite(slot ^ 1);       // chunk c+1 (regs loaded at iter c-1)
    if (c < 14) loadG(c + 2);             // issued BEFORE MFMA: ~1 iter of flight
#pragma unroll
    for (int mi = 0; mi < 4; mi++)
#pragma unroll
      for (int fj = 0; fj < 2; fj++)
        acc[mi][fj] = __builtin_amdgcn_mfma_f32_16x16x32_bf16(
            af0[mi], bf0[fj], acc[mi][fj], 0, 0, 0);
    // ---- k-slice 1 fragments ----
    short8 af1[4], bf1[2];
#pragma unroll
    for (int mi = 0; mi < 4; mi++)
      af1[mi] = *(const short8*)&Ard[slot * SLOT + aoff[mi] + ((32 + quad * 8) ^ swA[mi])];
#pragma unroll
    for (int fj = 0; fj < 2; fj++)
      bf1[fj] = *(const short8*)&Brd[slot * SLOT + boff[fj] + ((32 + quad * 8) ^ swB[fj])];
#pragma unroll
    for (int mi = 0; mi < 4; mi++)
#pragma unroll
      for (int fj = 0; fj < 2; fj++)
        acc[mi][fj] = __builtin_amdgcn_mfma_f32_16x16x32_bf16(
            af1[mi], bf1[fj], acc[mi][fj], 0, 0, 0);
  }

  // ---- epilogue: psum = sum W_de * G_de, W = C_ij (+ C_ji^T if offdiag) ----
  const int d0 = ti * 128, e0 = tj * 128;
  float psum = 0.f;
#pragma unroll
  for (int mi = 0; mi < 4; mi++) {
#pragma unroll
    for (int fj = 0; fj < 2; fj++) {
      const int dg = d0 + wm * 64 + mi * 16 + quad * 4;
      const int eg = e0 + wn * 32 + fj * 16 + l15;
#pragma unroll
      for (int r2 = 0; r2 < 4; r2++) {
        float wgt = C[(size_t)(dg + r2) * DDIM + eg];
        if (!diag) wgt += C[(size_t)eg * DDIM + dg + r2];
        psum += wgt * acc[mi][fj][r2];
      }
    }
  }

#pragma unroll
  for (int off = 32; off > 0; off >>= 1) psum += __shfl_down(psum, off);
  if (lane == 0) red[wave] = psum;
  if (sacc) {                             // park s partials (th < 256 only)
#pragma unroll
    for (int dd = 0; dd < 4; dd++) sred[(4 * tp + dd) * 8 + tn] = s_part[dd];
  }
  __syncthreads();
  if (th == 0) {
    const float tot = red[0] + red[1] + red[2] + red[3] +
                      red[4] + red[5] + red[6] + red[7];
    atomicAdd(out, tot * (1.0f / (float)NROWS));
  }
  if (diag && th < 128) {
    float sd = 0.f;
#pragma unroll
    for (int j = 0; j < 8; j++) sd += sred[th * 8 + j];
    atomicAdd(&s_ws[ti * 128 + th], sd);
  }
}

// ---- correction: out += -(1/N) sum_{d,e} C_de (coef_d mu_e + mu_d coef_e) ----
__global__ __launch_bounds__(256) void maha_corr(const float* __restrict__ C,
                                                 const float* __restrict__ mu,
                                                 const float* __restrict__ s_ws,
                                                 float* __restrict__ out) {
  __shared__ float red[4];
  const int b = blockIdx.x;               // 128 blocks x 4 d-rows
  const int th = threadIdx.x;
  float cd[4], md[4];
#pragma unroll
  for (int dd = 0; dd < 4; dd++) {
    const int d = b * 4 + dd;
    md[dd] = mu[d];
    cd[dd] = s_ws[d] - 0.5f * (float)NROWS * md[dd];
  }
  float p = 0.f;
#pragma unroll
  for (int rep = 0; rep < 2; rep++) {
    const int e = th + rep * 256;
    const float me = mu[e];
    const float ce = s_ws[e] - 0.5f * (float)NROWS * me;
#pragma unroll
    for (int dd = 0; dd < 4; dd++)
      p += C[(size_t)(b * 4 + dd) * DDIM + e] * (cd[dd] * me + md[dd] * ce);
  }
  const int lane = th & 63, wave = th >> 6;
#pragma unroll
  for (int off = 32; off > 0; off >>= 1) p += __shfl_down(p, off);
  if (lane == 0) red[wave] = p;
  __syncthreads();
  if (th == 0)
    atomicAdd(out, -(red[0] + red[1] + red[2] + red[3]) * (1.0f / (float)NROWS));
}

extern "C" void kernel_launch(void* const* d_in, const int* in_sizes, int n_in,
                              void* d_out, int out_size, void* d_ws, size_t ws_size,
                              hipStream_t stream) {
  const float* feature = (const float*)d_in[0];   // [131072, 512] fp32
  const float* mean    = (const float*)d_in[1];   // [512] fp32
  const float* invcov  = (const float*)d_in[2];   // [512, 512] fp32
  float* out = (float*)d_out;                     // scalar fp32
  float* s_ws = (float*)d_ws;                     // s[512] fp32 (2 KB)

  maha_zero<<<1, 512, 0, stream>>>(s_ws, out);
  maha_gram<<<1280, 512, 0, stream>>>(feature, invcov, s_ws, out);
  maha_corr<<<128, 256, 0, stream>>>(invcov, mean, s_ws, out);
}